// Round 1
// baseline (709.016 us; speedup 1.0000x reference)
//
#include <hip/hip_runtime.h>

#define Bb 2
#define Cc 64
#define Hh 48
#define Ww 48
#define Ll 48
#define HWc (Hh*Ww)          /* 2304 */
#define HWL (HWc*Ll)         /* 110592 */
#define GHh 24
#define SG (GHh*GHh*GHh)     /* 13824 */
#define CNT1f 110592.0f
#define CNT2f 9437184.0f     /* HW*C*C */

__device__ __forceinline__ unsigned f2k(float f){
  unsigned u = __float_as_uint(f);
  return (u & 0x80000000u) ? ~u : (u | 0x80000000u);
}
__device__ __forceinline__ float k2f(unsigned k){
  return (k & 0x80000000u) ? __uint_as_float(k & 0x7FFFFFFFu) : __uint_as_float(~k);
}
// half-pixel trilinear taps for 24 -> 48 (matches jax.image.resize 'trilinear')
__device__ __forceinline__ void interp1(int i, int& a, int& b, float& f){
  float src = i*0.5f - 0.25f;
  float fl = floorf(src);
  f = src - fl;
  int i0 = (int)fl;
  a = i0 < 0 ? 0 : i0;
  int i1 = i0 + 1;
  b = i1 > (GHh-1) ? (GHh-1) : i1;
}

__device__ __forceinline__ float blockMin256(float v, float* red, int t){
  red[t] = v; __syncthreads();
  #pragma unroll
  for (int s = 128; s >= 1; s >>= 1){
    if (t < s) red[t] = fminf(red[t], red[t+s]);
    __syncthreads();
  }
  float r = red[0];
  __syncthreads();
  return r;
}

__global__ void init_k(unsigned* keys, float* rowsum, float* s2){
  int t = threadIdx.x;
  if (t < 2) keys[t] = 0xFFFFFFFFu;
  if (t < 128) rowsum[t] = 0.f;
  if (t < 2) s2[t] = 0.f;
}

// out[b,o,s] = sum_c W[o,c]*in[b,c,s] + bias[o]; S spatial elems per batch (mult of 64)
__global__ __launch_bounds__(256) void conv_k(const float* __restrict__ in,
    const float* __restrict__ Wm, const float* __restrict__ bias,
    float* __restrict__ out, int S){
  __shared__ __align__(16) float Wl[64][68];   // Wl[c][o]
  __shared__ __align__(16) float xl[64][68];   // xl[c][s]
  int t = threadIdx.x;
  int ntile = S >> 6;
  int b  = blockIdx.x / ntile;
  int s0 = (blockIdx.x % ntile) << 6;
  for (int q = t; q < 4096; q += 256){
    int o = q >> 6, c = q & 63;
    Wl[c][o] = Wm[q];
  }
  const float* inb = in + (size_t)b*Cc*S + s0;
  for (int q = t; q < 1024; q += 256){
    int c = q >> 4, v = (q & 15) << 2;
    float4 val = *(const float4*)(inb + (size_t)c*S + v);
    *(float4*)&xl[c][v] = val;
  }
  __syncthreads();
  int o0 = (t & 15) << 2, s1 = (t >> 4) << 2;
  float a00=0,a01=0,a02=0,a03=0,a10=0,a11=0,a12=0,a13=0;
  float a20=0,a21=0,a22=0,a23=0,a30=0,a31=0,a32=0,a33=0;
  #pragma unroll 8
  for (int c = 0; c < 64; ++c){
    float4 wv = *(const float4*)&Wl[c][o0];
    float4 xv = *(const float4*)&xl[c][s1];
    a00 += wv.x*xv.x; a01 += wv.x*xv.y; a02 += wv.x*xv.z; a03 += wv.x*xv.w;
    a10 += wv.y*xv.x; a11 += wv.y*xv.y; a12 += wv.y*xv.z; a13 += wv.y*xv.w;
    a20 += wv.z*xv.x; a21 += wv.z*xv.y; a22 += wv.z*xv.z; a23 += wv.z*xv.w;
    a30 += wv.w*xv.x; a31 += wv.w*xv.y; a32 += wv.w*xv.z; a33 += wv.w*xv.w;
  }
  float* ob = out + (size_t)b*Cc*S + s0 + s1;
  float b0 = bias[o0+0], b1v = bias[o0+1], b2v = bias[o0+2], b3 = bias[o0+3];
  { float4 r = make_float4(a00+b0,a01+b0,a02+b0,a03+b0); *(float4*)(ob + (size_t)(o0+0)*S) = r; }
  { float4 r = make_float4(a10+b1v,a11+b1v,a12+b1v,a13+b1v); *(float4*)(ob + (size_t)(o0+1)*S) = r; }
  { float4 r = make_float4(a20+b2v,a21+b2v,a22+b2v,a23+b2v); *(float4*)(ob + (size_t)(o0+2)*S) = r; }
  { float4 r = make_float4(a30+b3,a31+b3,a32+b3,a33+b3); *(float4*)(ob + (size_t)(o0+3)*S) = r; }
}

// one block per (b,h,w): gate min/rowsum, theta_c_d min, S2 sum
__global__ __launch_bounds__(256) void reduce_k(const float* __restrict__ tx,
    const float* __restrict__ tgh, unsigned* __restrict__ keys,
    float* __restrict__ rowsum, float* __restrict__ s2){
  __shared__ __align__(16) float txt[48][68];   // [l][c]
  __shared__ __align__(16) float tgt[48][68];   // [l][c]
  __shared__ __align__(16) float th[64][97];    // [c][e*24+gl], e=(gh,gw) corner
  __shared__ float red[256];
  __shared__ float sxg[48];
  int t = threadIdx.x;
  int b = blockIdx.x / HWc, hw = blockIdx.x % HWc;
  int h = hw / Ww, w = hw % Ww;

  const float* txb = tx + ((size_t)b*Cc*HWc + hw)*Ll;
  for (int q = t; q < 768; q += 256){
    int c = q / 12, v = (q % 12) << 2;
    float4 val = *(const float4*)(txb + (size_t)c*HWL + v);
    txt[v+0][c]=val.x; txt[v+1][c]=val.y; txt[v+2][c]=val.z; txt[v+3][c]=val.w;
  }
  int ha, hb; float fh; interp1(h, ha, hb, fh);
  int wa, wb; float fw; interp1(w, wa, wb, fw);
  int ghs[2] = {ha, hb}, gws[2] = {wa, wb};
  for (int q = t; q < 1536; q += 256){
    int c = q / 24; int rem = q % 24; int e = rem / 6; int v = (rem % 6) << 2;
    const float* p = tgh + (((size_t)(b*Cc + c)*GHh + ghs[e>>1])*GHh + gws[e&1])*GHh + v;
    float4 val = *(const float4*)p;
    float* dst = &th[c][e*24 + v];
    dst[0]=val.x; dst[1]=val.y; dst[2]=val.z; dst[3]=val.w;
  }
  __syncthreads();
  float w00=(1.f-fh)*(1.f-fw), w01=(1.f-fh)*fw, w10=fh*(1.f-fw), w11=fh*fw;
  int c = t & 63, lg = t >> 6;
  float psum = 0.f, pmin = 3.4e38f;
  #pragma unroll
  for (int li = 0; li < 12; ++li){
    int l = lg*12 + li;
    int la, lb; float fl; interp1(l, la, lb, fl);
    float va = w00*th[c][la] + w01*th[c][24+la] + w10*th[c][48+la] + w11*th[c][72+la];
    float vb = w00*th[c][lb] + w01*th[c][24+lb] + w10*th[c][48+lb] + w11*th[c][72+lb];
    float tg = (1.f-fl)*va + fl*vb;
    tgt[l][c] = tg;
    float prod = txt[l][c]*tg;
    psum += prod;
    pmin = fminf(pmin, prod);
  }
  atomicAdd(&rowsum[b*Cc + c], psum);
  __syncthreads();  // tgt complete
  if (t < 48){
    float sx = 0.f, sg = 0.f;
    #pragma unroll 8
    for (int cc = 0; cc < 64; ++cc){ sx += txt[t][cc]; sg += tgt[t][cc]; }
    sxg[t] = sx*sg;
  }
  // theta_c_d raw[i,j] = sum_l txt[l][i]*tgt[l][j]; need global min
  int i0 = (t & 15) << 2, j0 = (t >> 4) << 2;
  float a00=0,a01=0,a02=0,a03=0,a10=0,a11=0,a12=0,a13=0;
  float a20=0,a21=0,a22=0,a23=0,a30=0,a31=0,a32=0,a33=0;
  #pragma unroll 4
  for (int l = 0; l < 48; ++l){
    float4 av = *(const float4*)&txt[l][i0];
    float4 bv = *(const float4*)&tgt[l][j0];
    a00 += av.x*bv.x; a01 += av.x*bv.y; a02 += av.x*bv.z; a03 += av.x*bv.w;
    a10 += av.y*bv.x; a11 += av.y*bv.y; a12 += av.y*bv.z; a13 += av.y*bv.w;
    a20 += av.z*bv.x; a21 += av.z*bv.y; a22 += av.z*bv.z; a23 += av.z*bv.w;
    a30 += av.w*bv.x; a31 += av.w*bv.y; a32 += av.w*bv.z; a33 += av.w*bv.w;
  }
  float amin = fminf(fminf(fminf(a00,a01),fminf(a02,a03)),
               fminf(fminf(fminf(a10,a11),fminf(a12,a13)),
               fminf(fminf(fminf(a20,a21),fminf(a22,a23)),
                     fminf(fminf(a30,a31),fminf(a32,a33)))));
  float m1p = blockMin256(pmin, red, t);
  float m2p = blockMin256(amin, red, t);
  if (t == 0){
    atomicMin(&keys[0], f2k(m1p));
    atomicMin(&keys[1], f2k(m2p));
    float tot = 0.f;
    for (int l = 0; l < 48; ++l) tot += sxg[l];
    atomicAdd(&s2[b], tot);
  }
}

// one block per (b,h,w): compute p and d
__global__ __launch_bounds__(256) void final_k(const float* __restrict__ x,
    const float* __restrict__ tx, const float* __restrict__ tgh,
    const unsigned* __restrict__ keys, const float* __restrict__ rowsum,
    const float* __restrict__ s2, float* __restrict__ outp, float* __restrict__ outd){
  __shared__ __align__(16) float txt[48][68];     // [l][c]
  __shared__ __align__(16) float tgt[48][68];     // [l][c]
  __shared__ __align__(16) float xs[64][52];      // [c][l]
  __shared__ __align__(16) float thAt[64*97];     // th[c][97] then aliased At[c][68]
  __shared__ float Xs[48];
  __shared__ float invd1[64];
  int t = threadIdx.x;
  int b = blockIdx.x / HWc, hw = blockIdx.x % HWc;
  int h = hw / Ww, w = hw % Ww;
  size_t sbase = ((size_t)b*Cc*HWc + hw)*Ll;
  const float* txb = tx + sbase;
  const float* xb  = x  + sbase;
  for (int q = t; q < 768; q += 256){
    int c = q / 12, v = (q % 12) << 2;
    float4 val = *(const float4*)(txb + (size_t)c*HWL + v);
    txt[v+0][c]=val.x; txt[v+1][c]=val.y; txt[v+2][c]=val.z; txt[v+3][c]=val.w;
    float4 xv = *(const float4*)(xb + (size_t)c*HWL + v);
    *(float4*)&xs[c][v] = xv;
  }
  int ha, hb; float fh; interp1(h, ha, hb, fh);
  int wa, wb; float fw; interp1(w, wa, wb, fw);
  int ghs[2] = {ha, hb}, gws[2] = {wa, wb};
  for (int q = t; q < 1536; q += 256){
    int c = q / 24; int rem = q % 24; int e = rem / 6; int v = (rem % 6) << 2;
    const float* p = tgh + (((size_t)(b*Cc + c)*GHh + ghs[e>>1])*GHh + gws[e&1])*GHh + v;
    float4 val = *(const float4*)p;
    float* dst = &thAt[c*97 + e*24 + v];
    dst[0]=val.x; dst[1]=val.y; dst[2]=val.z; dst[3]=val.w;
  }
  __syncthreads();
  if (t < 48){
    float s = 0.f;
    #pragma unroll 8
    for (int cc = 0; cc < 64; ++cc) s += xs[cc][t];
    Xs[t] = s;
  }
  float m1 = k2f(keys[0]), m2 = k2f(keys[1]);
  if (t < 64) invd1[t] = 1.f/(rowsum[b*Cc + t] - m1*CNT1f);
  float invd2 = 1.f/(s2[b] - m2*CNT2f);
  float w00=(1.f-fh)*(1.f-fw), w01=(1.f-fh)*fw, w10=fh*(1.f-fw), w11=fh*fw;
  int c = t & 63, lg = t >> 6;
  #pragma unroll
  for (int li = 0; li < 12; ++li){
    int l = lg*12 + li;
    int la, lb; float fl; interp1(l, la, lb, fl);
    const float* thc = &thAt[c*97];
    float va = w00*thc[la] + w01*thc[24+la] + w10*thc[48+la] + w11*thc[72+la];
    float vb = w00*thc[lb] + w01*thc[24+lb] + w10*thc[48+lb] + w11*thc[72+lb];
    tgt[l][c] = (1.f-fl)*va + fl*vb;
  }
  __syncthreads();  // tgt, Xs, invd1 ready; th no longer needed
  // p = (tx*tg - m1) * x / denom1[b,c]
  #pragma unroll
  for (int k = 0; k < 12; ++k){
    int e = t + (k << 8);
    int cc = e / 48, l = e % 48;
    float xv = xb[(size_t)cc*HWL + l];
    float pv = (txt[l][cc]*tgt[l][cc] - m1)*invd1[cc]*xv;
    outp[sbase + (size_t)cc*HWL + l] = pv;
  }
  // At[c][j] = raw theta_c_d = sum_l txt[l][c]*tgt[l][j]  (overwrites th region)
  int c0 = (t & 15) << 2, j0 = (t >> 4) << 2;
  float a00=0,a01=0,a02=0,a03=0,a10=0,a11=0,a12=0,a13=0;
  float a20=0,a21=0,a22=0,a23=0,a30=0,a31=0,a32=0,a33=0;
  #pragma unroll 4
  for (int l = 0; l < 48; ++l){
    float4 av = *(const float4*)&txt[l][c0];
    float4 bv = *(const float4*)&tgt[l][j0];
    a00 += av.x*bv.x; a01 += av.x*bv.y; a02 += av.x*bv.z; a03 += av.x*bv.w;
    a10 += av.y*bv.x; a11 += av.y*bv.y; a12 += av.y*bv.z; a13 += av.y*bv.w;
    a20 += av.z*bv.x; a21 += av.z*bv.y; a22 += av.z*bv.z; a23 += av.z*bv.w;
    a30 += av.w*bv.x; a31 += av.w*bv.y; a32 += av.w*bv.z; a33 += av.w*bv.w;
  }
  { float4 r = make_float4(a00,a01,a02,a03); *(float4*)&thAt[(c0+0)*68 + j0] = r; }
  { float4 r = make_float4(a10,a11,a12,a13); *(float4*)&thAt[(c0+1)*68 + j0] = r; }
  { float4 r = make_float4(a20,a21,a22,a23); *(float4*)&thAt[(c0+2)*68 + j0] = r; }
  { float4 r = make_float4(a30,a31,a32,a33); *(float4*)&thAt[(c0+3)*68 + j0] = r; }
  __syncthreads();
  // d[j,l] = (sum_c xs[c][l]*At[c][j] - m2*Xs[l]) * invd2
  if (t < 192){
    int jj = (t & 15) << 2, l0 = (t >> 4) << 2;
    float d00=0,d01=0,d02=0,d03=0,d10=0,d11=0,d12=0,d13=0;
    float d20=0,d21=0,d22=0,d23=0,d30=0,d31=0,d32=0,d33=0;
    #pragma unroll 4
    for (int cc = 0; cc < 64; ++cc){
      float4 av = *(const float4*)&thAt[cc*68 + jj];
      float4 xv = *(const float4*)&xs[cc][l0];
      d00 += av.x*xv.x; d01 += av.x*xv.y; d02 += av.x*xv.z; d03 += av.x*xv.w;
      d10 += av.y*xv.x; d11 += av.y*xv.y; d12 += av.y*xv.z; d13 += av.y*xv.w;
      d20 += av.z*xv.x; d21 += av.z*xv.y; d22 += av.z*xv.z; d23 += av.z*xv.w;
      d30 += av.w*xv.x; d31 += av.w*xv.y; d32 += av.w*xv.z; d33 += av.w*xv.w;
    }
    float xs0 = m2*Xs[l0+0], xs1 = m2*Xs[l0+1], xs2 = m2*Xs[l0+2], xs3 = m2*Xs[l0+3];
    { float4 r = make_float4((d00-xs0)*invd2,(d01-xs1)*invd2,(d02-xs2)*invd2,(d03-xs3)*invd2);
      *(float4*)(outd + sbase + (size_t)(jj+0)*HWL + l0) = r; }
    { float4 r = make_float4((d10-xs0)*invd2,(d11-xs1)*invd2,(d12-xs2)*invd2,(d13-xs3)*invd2);
      *(float4*)(outd + sbase + (size_t)(jj+1)*HWL + l0) = r; }
    { float4 r = make_float4((d20-xs0)*invd2,(d21-xs1)*invd2,(d22-xs2)*invd2,(d23-xs3)*invd2);
      *(float4*)(outd + sbase + (size_t)(jj+2)*HWL + l0) = r; }
    { float4 r = make_float4((d30-xs0)*invd2,(d31-xs1)*invd2,(d32-xs2)*invd2,(d33-xs3)*invd2);
      *(float4*)(outd + sbase + (size_t)(jj+3)*HWL + l0) = r; }
  }
}

extern "C" void kernel_launch(void* const* d_in, const int* in_sizes, int n_in,
                              void* d_out, int out_size, void* d_ws, size_t ws_size,
                              hipStream_t stream){
  (void)in_sizes; (void)n_in; (void)out_size; (void)ws_size;
  const float* x  = (const float*)d_in[0];
  const float* g  = (const float*)d_in[1];
  const float* W1 = (const float*)d_in[2];
  const float* b1 = (const float*)d_in[3];
  const float* W2 = (const float*)d_in[4];
  const float* b2 = (const float*)d_in[5];
  float* outp = (float*)d_out;
  float* outd = outp + (size_t)Bb*Cc*HWL;
  float* ws   = (float*)d_ws;
  float* txw  = ws;                      // theta_x: 14155776 floats
  float* tghw = ws + (size_t)Bb*Cc*HWL;  // theta_g half-res: 1769472 floats
  float* accf = tghw + (size_t)Bb*Cc*SG;
  unsigned* keys = (unsigned*)accf;      // [0]=gmin1 key, [1]=gmin2 key
  float* rowsum  = accf + 2;             // 128 per-(b,c) raw gate sums
  float* s2      = accf + 130;           // 2 per-b raw theta_c_d sums

  hipLaunchKernelGGL(init_k, dim3(1), dim3(256), 0, stream, keys, rowsum, s2);
  hipLaunchKernelGGL(conv_k, dim3(Bb*(SG/64)), dim3(256), 0, stream, g, W2, b2, tghw, SG);
  hipLaunchKernelGGL(conv_k, dim3(Bb*(HWL/64)), dim3(256), 0, stream, x, W1, b1, txw, HWL);
  hipLaunchKernelGGL(reduce_k, dim3(Bb*HWc), dim3(256), 0, stream, txw, tghw, keys, rowsum, s2);
  hipLaunchKernelGGL(final_k, dim3(Bb*HWc), dim3(256), 0, stream, x, txw, tghw, keys, rowsum, s2, outp, outd);
}

// Round 2
// 462.755 us; speedup vs baseline: 1.5322x; 1.5322x over previous
//
#include <hip/hip_runtime.h>

#define Bb 2
#define Cc 64
#define Hh 48
#define Ww 48
#define Ll 48
#define HWc (Hh*Ww)          /* 2304 */
#define HWL (HWc*Ll)         /* 110592 */
#define GHh 24
#define SG (GHh*GHh*GHh)     /* 13824 */
#define NBLK (Bb*HWc)        /* 4608 */
#define CNT1f 110592.0f
#define CNT2f 9437184.0f     /* HW*C*C */

// half-pixel trilinear taps for 24 -> 48 (matches jax.image.resize 'trilinear')
__device__ __forceinline__ void interp1(int i, int& a, int& b, float& f){
  float src = i*0.5f - 0.25f;
  float fl = floorf(src);
  f = src - fl;
  int i0 = (int)fl;
  a = i0 < 0 ? 0 : i0;
  int i1 = i0 + 1;
  b = i1 > (GHh-1) ? (GHh-1) : i1;
}

// out[b,o,s] = sum_c W[o,c]*in[b,c,s] + bias[o]
__global__ __launch_bounds__(256) void conv_k(const float* __restrict__ in,
    const float* __restrict__ Wm, const float* __restrict__ bias,
    float* __restrict__ out, int S){
  __shared__ __align__(16) float Wl[64][68];   // Wl[c][o]
  __shared__ __align__(16) float xl[64][68];   // xl[c][s]
  int t = threadIdx.x;
  int ntile = S >> 6;
  int b  = blockIdx.x / ntile;
  int s0 = (blockIdx.x % ntile) << 6;
  for (int q = t; q < 4096; q += 256){
    int o = q >> 6, c = q & 63;
    Wl[c][o] = Wm[q];
  }
  const float* inb = in + (size_t)b*Cc*S + s0;
  for (int q = t; q < 1024; q += 256){
    int c = q >> 4, v = (q & 15) << 2;
    float4 val = *(const float4*)(inb + (size_t)c*S + v);
    *(float4*)&xl[c][v] = val;
  }
  __syncthreads();
  int o0 = (t & 15) << 2, s1 = (t >> 4) << 2;
  float a00=0,a01=0,a02=0,a03=0,a10=0,a11=0,a12=0,a13=0;
  float a20=0,a21=0,a22=0,a23=0,a30=0,a31=0,a32=0,a33=0;
  #pragma unroll 8
  for (int c = 0; c < 64; ++c){
    float4 wv = *(const float4*)&Wl[c][o0];
    float4 xv = *(const float4*)&xl[c][s1];
    a00 += wv.x*xv.x; a01 += wv.x*xv.y; a02 += wv.x*xv.z; a03 += wv.x*xv.w;
    a10 += wv.y*xv.x; a11 += wv.y*xv.y; a12 += wv.y*xv.z; a13 += wv.y*xv.w;
    a20 += wv.z*xv.x; a21 += wv.z*xv.y; a22 += wv.z*xv.z; a23 += wv.z*xv.w;
    a30 += wv.w*xv.x; a31 += wv.w*xv.y; a32 += wv.w*xv.z; a33 += wv.w*xv.w;
  }
  float* ob = out + (size_t)b*Cc*S + s0 + s1;
  float b0 = bias[o0+0], b1v = bias[o0+1], b2v = bias[o0+2], b3 = bias[o0+3];
  { float4 r = make_float4(a00+b0,a01+b0,a02+b0,a03+b0); *(float4*)(ob + (size_t)(o0+0)*S) = r; }
  { float4 r = make_float4(a10+b1v,a11+b1v,a12+b1v,a13+b1v); *(float4*)(ob + (size_t)(o0+1)*S) = r; }
  { float4 r = make_float4(a20+b2v,a21+b2v,a22+b2v,a23+b2v); *(float4*)(ob + (size_t)(o0+2)*S) = r; }
  { float4 r = make_float4(a30+b3,a31+b3,a32+b3,a33+b3); *(float4*)(ob + (size_t)(o0+3)*S) = r; }
}

// materialize full-resolution theta_g: (B,C,24^3) -> (B,C,48^3)
// one block per (b*C + c, h)
__global__ __launch_bounds__(256) void upsample_k(const float* __restrict__ tgh,
    float* __restrict__ tg){
  __shared__ float shm[2][24][25];
  int t = threadIdx.x;
  int bc = blockIdx.x / Hh;
  int h  = blockIdx.x % Hh;
  int ha, hb; float fh; interp1(h, ha, hb, fh);
  const float* src = tgh + (size_t)bc*SG;
  for (int q = t; q < 288; q += 256){
    int p = q / 144, rem = q % 144;
    int w_ = rem / 6, vl = (rem % 6) << 2;
    int hs = p ? hb : ha;
    float4 v = *(const float4*)(src + (size_t)hs*576 + w_*24 + vl);
    shm[p][w_][vl+0]=v.x; shm[p][w_][vl+1]=v.y; shm[p][w_][vl+2]=v.z; shm[p][w_][vl+3]=v.w;
  }
  __syncthreads();
  float* dst = tg + ((size_t)bc*Hh + h)*HWc;
  float omf = 1.f - fh;
  #pragma unroll
  for (int k = 0; k < 9; ++k){
    int idx = t + (k << 8);          // 0..2303
    int w = idx / 48, l = idx % 48;
    int wa, wb; float fw; interp1(w, wa, wb, fw);
    int la, lb; float fl; interp1(l, la, lb, fl);
    float vaa = omf*shm[0][wa][la] + fh*shm[1][wa][la];
    float vab = omf*shm[0][wa][lb] + fh*shm[1][wa][lb];
    float vba = omf*shm[0][wb][la] + fh*shm[1][wb][la];
    float vbb = omf*shm[0][wb][lb] + fh*shm[1][wb][lb];
    float va = (1.f-fw)*vaa + fw*vba;
    float vb = (1.f-fw)*vab + fw*vbb;
    dst[idx] = (1.f-fl)*va + fl*vb;
  }
}

// one block per (b,h,w): per-block partials (no global atomics)
__global__ __launch_bounds__(256) void reduce_k(const float* __restrict__ tx,
    const float* __restrict__ tg, float* __restrict__ part_row,
    float* __restrict__ pm1, float* __restrict__ pm2, float* __restrict__ ps2){
  __shared__ __align__(16) float txt[48][68];   // [l][c]
  __shared__ __align__(16) float tgt[48][68];   // [l][c]
  __shared__ float red[512];
  __shared__ float sxg[48];
  int t = threadIdx.x;
  int bIdx = blockIdx.x;
  int b = bIdx / HWc, hw = bIdx % HWc;
  const float* txb = tx + ((size_t)b*Cc*HWc + hw)*Ll;
  const float* tgb = tg + ((size_t)b*Cc*HWc + hw)*Ll;
  for (int q = t; q < 768; q += 256){
    int c = q / 12, v = (q % 12) << 2;
    float4 a = *(const float4*)(txb + (size_t)c*HWL + v);
    txt[v+0][c]=a.x; txt[v+1][c]=a.y; txt[v+2][c]=a.z; txt[v+3][c]=a.w;
    float4 g = *(const float4*)(tgb + (size_t)c*HWL + v);
    tgt[v+0][c]=g.x; tgt[v+1][c]=g.y; tgt[v+2][c]=g.z; tgt[v+3][c]=g.w;
  }
  __syncthreads();
  int c = t & 63, lg = t >> 6;
  float psum = 0.f, pmin = 3.4e38f;
  #pragma unroll
  for (int li = 0; li < 12; ++li){
    int l = lg*12 + li;
    float prod = txt[l][c]*tgt[l][c];
    psum += prod;
    pmin = fminf(pmin, prod);
  }
  red[t] = psum;
  if (t < 48){
    float sx = 0.f, sg = 0.f;
    #pragma unroll 8
    for (int cc = 0; cc < 64; ++cc){ sx += txt[t][cc]; sg += tgt[t][cc]; }
    sxg[t] = sx*sg;
  }
  __syncthreads();
  if (t < 64) part_row[(size_t)bIdx*64 + t] = red[t]+red[t+64]+red[t+128]+red[t+192];
  // raw theta_c_d[i,j] = sum_l txt[l][i]*tgt[l][j]; block min
  int i0 = (t & 15) << 2, j0 = (t >> 4) << 2;
  float a00=0,a01=0,a02=0,a03=0,a10=0,a11=0,a12=0,a13=0;
  float a20=0,a21=0,a22=0,a23=0,a30=0,a31=0,a32=0,a33=0;
  #pragma unroll 4
  for (int l = 0; l < 48; ++l){
    float4 av = *(const float4*)&txt[l][i0];
    float4 bv = *(const float4*)&tgt[l][j0];
    a00 += av.x*bv.x; a01 += av.x*bv.y; a02 += av.x*bv.z; a03 += av.x*bv.w;
    a10 += av.y*bv.x; a11 += av.y*bv.y; a12 += av.y*bv.z; a13 += av.y*bv.w;
    a20 += av.z*bv.x; a21 += av.z*bv.y; a22 += av.z*bv.z; a23 += av.z*bv.w;
    a30 += av.w*bv.x; a31 += av.w*bv.y; a32 += av.w*bv.z; a33 += av.w*bv.w;
  }
  float amin = fminf(fminf(fminf(a00,a01),fminf(a02,a03)),
               fminf(fminf(fminf(a10,a11),fminf(a12,a13)),
               fminf(fminf(fminf(a20,a21),fminf(a22,a23)),
                     fminf(fminf(a30,a31),fminf(a32,a33)))));
  __syncthreads();            // red reads (part_row) done
  red[t] = pmin; red[256+t] = amin;
  __syncthreads();
  if (t < 128){
    red[t] = fminf(red[t], red[t+128]);
    red[256+t] = fminf(red[256+t], red[256+t+128]);
  }
  __syncthreads();
  if (t < 64){
    float v1 = fminf(red[t], red[t+64]);
    float v2 = fminf(red[256+t], red[256+t+64]);
    #pragma unroll
    for (int off = 32; off; off >>= 1){
      v1 = fminf(v1, __shfl_down(v1, off));
      v2 = fminf(v2, __shfl_down(v2, off));
    }
    if (t == 0){
      pm1[bIdx] = v1; pm2[bIdx] = v2;
      float tot = 0.f;
      #pragma unroll
      for (int l = 0; l < 48; ++l) tot += sxg[l];
      ps2[bIdx] = tot;
    }
  }
}

// tiny second-stage reduction: 4 blocks
__global__ __launch_bounds__(256) void reduce2_k(const float* __restrict__ part_row,
    const float* __restrict__ pm1, const float* __restrict__ pm2,
    const float* __restrict__ ps2, float* __restrict__ rowsum,
    float* __restrict__ gmin, float* __restrict__ s2v){
  __shared__ float red[512];
  int t = threadIdx.x, blk = blockIdx.x;
  if (blk < 2){
    int c = t & 63, seg = t >> 6;
    float s = 0.f;
    for (int i = seg; i < HWc; i += 4) s += part_row[((size_t)(blk*HWc + i))*64 + c];
    red[t] = s; __syncthreads();
    if (t < 64) rowsum[blk*64 + t] = red[t]+red[t+64]+red[t+128]+red[t+192];
  } else if (blk == 2){
    float m1 = 3.4e38f, m2 = 3.4e38f;
    for (int i = t; i < NBLK; i += 256){ m1 = fminf(m1, pm1[i]); m2 = fminf(m2, pm2[i]); }
    red[t] = m1; red[256+t] = m2; __syncthreads();
    for (int s = 128; s >= 1; s >>= 1){
      if (t < s){ red[t] = fminf(red[t], red[t+s]); red[256+t] = fminf(red[256+t], red[256+t+s]); }
      __syncthreads();
    }
    if (t == 0){ gmin[0] = red[0]; gmin[1] = red[256]; }
  } else {
    float sa = 0.f, sb = 0.f;
    for (int i = t; i < HWc; i += 256){ sa += ps2[i]; sb += ps2[HWc + i]; }
    red[t] = sa; red[256+t] = sb; __syncthreads();
    for (int s = 128; s >= 1; s >>= 1){
      if (t < s){ red[t] += red[t+s]; red[256+t] += red[256+t+s]; }
      __syncthreads();
    }
    if (t == 0){ s2v[0] = red[0]; s2v[1] = red[256]; }
  }
}

// one block per (b,h,w): compute p and d
__global__ __launch_bounds__(256) void final_k(const float* __restrict__ x,
    const float* __restrict__ tx, const float* __restrict__ tg,
    const float* __restrict__ gmin, const float* __restrict__ rowsum,
    const float* __restrict__ s2v, float* __restrict__ outp, float* __restrict__ outd){
  __shared__ __align__(16) float sh[6528 + 3328 + 48 + 64];
  float* txt = sh;           // [48][68]  l*68+c
  float* tgt = sh + 3264;    // [48][68]
  float* At  = sh;           // [64][68] aliased over txt/tgt after they die
  float* xs  = sh + 6528;    // [64][52]  c*52+l
  float* Xs  = sh + 6528 + 3328;   // [48]
  float* iv1 = Xs + 48;            // [64]
  int t = threadIdx.x;
  int bIdx = blockIdx.x;
  int b = bIdx / HWc, hw = bIdx % HWc;
  size_t sbase = ((size_t)b*Cc*HWc + hw)*Ll;
  const float* txb = tx + sbase;
  const float* tgb = tg + sbase;
  const float* xb  = x  + sbase;
  for (int q = t; q < 768; q += 256){
    int c = q / 12, v = (q % 12) << 2;
    float4 a = *(const float4*)(txb + (size_t)c*HWL + v);
    txt[(v+0)*68+c]=a.x; txt[(v+1)*68+c]=a.y; txt[(v+2)*68+c]=a.z; txt[(v+3)*68+c]=a.w;
    float4 g = *(const float4*)(tgb + (size_t)c*HWL + v);
    tgt[(v+0)*68+c]=g.x; tgt[(v+1)*68+c]=g.y; tgt[(v+2)*68+c]=g.z; tgt[(v+3)*68+c]=g.w;
    float4 xv = *(const float4*)(xb + (size_t)c*HWL + v);
    *(float4*)&xs[c*52 + v] = xv;
  }
  __syncthreads();
  if (t < 48){
    float s = 0.f;
    #pragma unroll 8
    for (int cc = 0; cc < 64; ++cc) s += xs[cc*52 + t];
    Xs[t] = s;
  }
  float m1 = gmin[0], m2 = gmin[1];
  if (t < 64) iv1[t] = 1.f/(rowsum[b*64 + t] - m1*CNT1f);
  float invd2 = 1.f/(s2v[b] - m2*CNT2f);
  // At accumulation in registers (reads txt/tgt)
  int i0 = (t & 15) << 2, j0 = (t >> 4) << 2;
  float a00=0,a01=0,a02=0,a03=0,a10=0,a11=0,a12=0,a13=0;
  float a20=0,a21=0,a22=0,a23=0,a30=0,a31=0,a32=0,a33=0;
  #pragma unroll 4
  for (int l = 0; l < 48; ++l){
    float4 av = *(const float4*)&txt[l*68 + i0];
    float4 bv = *(const float4*)&tgt[l*68 + j0];
    a00 += av.x*bv.x; a01 += av.x*bv.y; a02 += av.x*bv.z; a03 += av.x*bv.w;
    a10 += av.y*bv.x; a11 += av.y*bv.y; a12 += av.y*bv.z; a13 += av.y*bv.w;
    a20 += av.z*bv.x; a21 += av.z*bv.y; a22 += av.z*bv.z; a23 += av.z*bv.w;
    a30 += av.w*bv.x; a31 += av.w*bv.y; a32 += av.w*bv.z; a33 += av.w*bv.w;
  }
  __syncthreads();   // Xs/iv1 visible; all still need txt/tgt for p
  // p = (tx*tg - m1)*invd1[c]*x
  #pragma unroll
  for (int k = 0; k < 12; ++k){
    int e = t + (k << 8);
    int cc = e / 48, l = e % 48;
    float pv = (txt[l*68+cc]*tgt[l*68+cc] - m1)*iv1[cc]*xs[cc*52+l];
    outp[sbase + (size_t)cc*HWL + l] = pv;
  }
  __syncthreads();   // p reads of txt/tgt done; safe to overwrite with At
  { float4 r = make_float4(a00,a01,a02,a03); *(float4*)&At[(i0+0)*68 + j0] = r; }
  { float4 r = make_float4(a10,a11,a12,a13); *(float4*)&At[(i0+1)*68 + j0] = r; }
  { float4 r = make_float4(a20,a21,a22,a23); *(float4*)&At[(i0+2)*68 + j0] = r; }
  { float4 r = make_float4(a30,a31,a32,a33); *(float4*)&At[(i0+3)*68 + j0] = r; }
  __syncthreads();
  // d[j,l] = (sum_c xs[c][l]*At[c][j] - m2*Xs[l]) * invd2
  if (t < 192){
    int jj = (t & 15) << 2, l0 = (t >> 4) << 2;
    float d00=0,d01=0,d02=0,d03=0,d10=0,d11=0,d12=0,d13=0;
    float d20=0,d21=0,d22=0,d23=0,d30=0,d31=0,d32=0,d33=0;
    #pragma unroll 4
    for (int cc = 0; cc < 64; ++cc){
      float4 av = *(const float4*)&At[cc*68 + jj];
      float4 xv = *(const float4*)&xs[cc*52 + l0];
      d00 += av.x*xv.x; d01 += av.x*xv.y; d02 += av.x*xv.z; d03 += av.x*xv.w;
      d10 += av.y*xv.x; d11 += av.y*xv.y; d12 += av.y*xv.z; d13 += av.y*xv.w;
      d20 += av.z*xv.x; d21 += av.z*xv.y; d22 += av.z*xv.z; d23 += av.z*xv.w;
      d30 += av.w*xv.x; d31 += av.w*xv.y; d32 += av.w*xv.z; d33 += av.w*xv.w;
    }
    float xs0 = m2*Xs[l0+0], xs1 = m2*Xs[l0+1], xs2 = m2*Xs[l0+2], xs3 = m2*Xs[l0+3];
    { float4 r = make_float4((d00-xs0)*invd2,(d01-xs1)*invd2,(d02-xs2)*invd2,(d03-xs3)*invd2);
      *(float4*)(outd + sbase + (size_t)(jj+0)*HWL + l0) = r; }
    { float4 r = make_float4((d10-xs0)*invd2,(d11-xs1)*invd2,(d12-xs2)*invd2,(d13-xs3)*invd2);
      *(float4*)(outd + sbase + (size_t)(jj+1)*HWL + l0) = r; }
    { float4 r = make_float4((d20-xs0)*invd2,(d21-xs1)*invd2,(d22-xs2)*invd2,(d23-xs3)*invd2);
      *(float4*)(outd + sbase + (size_t)(jj+2)*HWL + l0) = r; }
    { float4 r = make_float4((d30-xs0)*invd2,(d31-xs1)*invd2,(d32-xs2)*invd2,(d33-xs3)*invd2);
      *(float4*)(outd + sbase + (size_t)(jj+3)*HWL + l0) = r; }
  }
}

extern "C" void kernel_launch(void* const* d_in, const int* in_sizes, int n_in,
                              void* d_out, int out_size, void* d_ws, size_t ws_size,
                              hipStream_t stream){
  (void)in_sizes; (void)n_in; (void)out_size; (void)ws_size;
  const float* x  = (const float*)d_in[0];
  const float* g  = (const float*)d_in[1];
  const float* W1 = (const float*)d_in[2];
  const float* b1 = (const float*)d_in[3];
  const float* W2 = (const float*)d_in[4];
  const float* b2 = (const float*)d_in[5];
  float* outp = (float*)d_out;
  float* outd = outp + (size_t)Bb*Cc*HWL;
  float* ws   = (float*)d_ws;
  float* txw  = ws;                               // 14,155,776
  float* tgw  = txw + (size_t)Bb*Cc*HWL;          // 14,155,776 (full-res theta_g)
  float* tghw = tgw + (size_t)Bb*Cc*HWL;          // 1,769,472
  float* part_row = tghw + (size_t)Bb*Cc*SG;      // NBLK*64
  float* pm1 = part_row + (size_t)NBLK*64;        // NBLK
  float* pm2 = pm1 + NBLK;                        // NBLK
  float* ps2 = pm2 + NBLK;                        // NBLK
  float* rowsum = ps2 + NBLK;                     // 128
  float* gmin = rowsum + 128;                     // 2
  float* s2v  = gmin + 2;                         // 2

  hipLaunchKernelGGL(conv_k, dim3(Bb*(SG/64)), dim3(256), 0, stream, g, W2, b2, tghw, SG);
  hipLaunchKernelGGL(conv_k, dim3(Bb*(HWL/64)), dim3(256), 0, stream, x, W1, b1, txw, HWL);
  hipLaunchKernelGGL(upsample_k, dim3(Bb*Cc*Hh), dim3(256), 0, stream, tghw, tgw);
  hipLaunchKernelGGL(reduce_k, dim3(NBLK), dim3(256), 0, stream, txw, tgw, part_row, pm1, pm2, ps2);
  hipLaunchKernelGGL(reduce2_k, dim3(4), dim3(256), 0, stream, part_row, pm1, pm2, ps2, rowsum, gmin, s2v);
  hipLaunchKernelGGL(final_k, dim3(NBLK), dim3(256), 0, stream, x, txw, tgw, gmin, rowsum, s2v, outp, outd);
}

// Round 3
// 334.643 us; speedup vs baseline: 2.1187x; 1.3828x over previous
//
#include <hip/hip_runtime.h>

#define Bb 2
#define Cc 64
#define Hh 48
#define Ww 48
#define Ll 48
#define HWc (Hh*Ww)          /* 2304 */
#define HWL (HWc*Ll)         /* 110592 */
#define GHh 24
#define SG (GHh*GHh*GHh)     /* 13824 */
#define NBLK (Bb*HWc)        /* 4608 */
#define CNT1f 110592.0f
#define CNT2f 9437184.0f     /* HW*C*C */

// half-pixel trilinear taps for 24 -> 48 (matches jax.image.resize 'trilinear')
__device__ __forceinline__ void interp1(int i, int& a, int& b, float& f){
  float src = i*0.5f - 0.25f;
  float fl = floorf(src);
  f = src - fl;
  int i0 = (int)fl;
  a = i0 < 0 ? 0 : i0;
  int i1 = i0 + 1;
  b = i1 > (GHh-1) ? (GHh-1) : i1;
}

// out[b,o,s] = sum_c W[o,c]*in[b,c,s] + bias[o]
__global__ __launch_bounds__(256) void conv_k(const float* __restrict__ in,
    const float* __restrict__ Wm, const float* __restrict__ bias,
    float* __restrict__ out, int S){
  __shared__ __align__(16) float Wl[64][68];   // Wl[c][o]
  __shared__ __align__(16) float xl[64][68];   // xl[c][s]
  int t = threadIdx.x;
  int ntile = S >> 6;
  int b  = blockIdx.x / ntile;
  int s0 = (blockIdx.x % ntile) << 6;
  for (int q = t; q < 4096; q += 256){
    int o = q >> 6, c = q & 63;
    Wl[c][o] = Wm[q];
  }
  const float* inb = in + (size_t)b*Cc*S + s0;
  for (int q = t; q < 1024; q += 256){
    int c = q >> 4, v = (q & 15) << 2;
    float4 val = *(const float4*)(inb + (size_t)c*S + v);
    *(float4*)&xl[c][v] = val;
  }
  __syncthreads();
  int o0 = (t & 15) << 2, s1 = (t >> 4) << 2;
  float a00=0,a01=0,a02=0,a03=0,a10=0,a11=0,a12=0,a13=0;
  float a20=0,a21=0,a22=0,a23=0,a30=0,a31=0,a32=0,a33=0;
  #pragma unroll 8
  for (int c = 0; c < 64; ++c){
    float4 wv = *(const float4*)&Wl[c][o0];
    float4 xv = *(const float4*)&xl[c][s1];
    a00 += wv.x*xv.x; a01 += wv.x*xv.y; a02 += wv.x*xv.z; a03 += wv.x*xv.w;
    a10 += wv.y*xv.x; a11 += wv.y*xv.y; a12 += wv.y*xv.z; a13 += wv.y*xv.w;
    a20 += wv.z*xv.x; a21 += wv.z*xv.y; a22 += wv.z*xv.z; a23 += wv.z*xv.w;
    a30 += wv.w*xv.x; a31 += wv.w*xv.y; a32 += wv.w*xv.z; a33 += wv.w*xv.w;
  }
  float* ob = out + (size_t)b*Cc*S + s0 + s1;
  float b0 = bias[o0+0], b1v = bias[o0+1], b2v = bias[o0+2], b3 = bias[o0+3];
  { float4 r = make_float4(a00+b0,a01+b0,a02+b0,a03+b0); *(float4*)(ob + (size_t)(o0+0)*S) = r; }
  { float4 r = make_float4(a10+b1v,a11+b1v,a12+b1v,a13+b1v); *(float4*)(ob + (size_t)(o0+1)*S) = r; }
  { float4 r = make_float4(a20+b2v,a21+b2v,a22+b2v,a23+b2v); *(float4*)(ob + (size_t)(o0+2)*S) = r; }
  { float4 r = make_float4(a30+b3,a31+b3,a32+b3,a33+b3); *(float4*)(ob + (size_t)(o0+3)*S) = r; }
}

// materialize full-resolution theta_g: (B,C,24^3) -> (B,C,48^3)
// one block per (b*C + c, h)
__global__ __launch_bounds__(256) void upsample_k(const float* __restrict__ tgh,
    float* __restrict__ tg){
  __shared__ float shm[2][24][25];
  int t = threadIdx.x;
  int bc = blockIdx.x / Hh;
  int h  = blockIdx.x % Hh;
  int ha, hb; float fh; interp1(h, ha, hb, fh);
  const float* src = tgh + (size_t)bc*SG;
  for (int q = t; q < 288; q += 256){
    int p = q / 144, rem = q % 144;
    int w_ = rem / 6, vl = (rem % 6) << 2;
    int hs = p ? hb : ha;
    float4 v = *(const float4*)(src + (size_t)hs*576 + w_*24 + vl);
    shm[p][w_][vl+0]=v.x; shm[p][w_][vl+1]=v.y; shm[p][w_][vl+2]=v.z; shm[p][w_][vl+3]=v.w;
  }
  __syncthreads();
  float* dst = tg + ((size_t)bc*Hh + h)*HWc;
  float omf = 1.f - fh;
  #pragma unroll
  for (int k = 0; k < 9; ++k){
    int idx = t + (k << 8);          // 0..2303
    int w = idx / 48, l = idx % 48;
    int wa, wb; float fw; interp1(w, wa, wb, fw);
    int la, lb; float fl; interp1(l, la, lb, fl);
    float vaa = omf*shm[0][wa][la] + fh*shm[1][wa][la];
    float vab = omf*shm[0][wa][lb] + fh*shm[1][wa][lb];
    float vba = omf*shm[0][wb][la] + fh*shm[1][wb][la];
    float vbb = omf*shm[0][wb][lb] + fh*shm[1][wb][lb];
    float va = (1.f-fw)*vaa + fw*vba;
    float vb = (1.f-fw)*vab + fw*vbb;
    dst[idx] = (1.f-fl)*va + fl*vb;
  }
}

// one block per (b,h,w): per-block partials (no global atomics)
__global__ __launch_bounds__(256) void reduce_k(const float* __restrict__ tx,
    const float* __restrict__ tg, float* __restrict__ part_row,
    float* __restrict__ pm1, float* __restrict__ pm2, float* __restrict__ ps2){
  __shared__ __align__(16) float txt[48][68];   // [l][c]
  __shared__ __align__(16) float tgt[48][68];   // [l][c]
  __shared__ float red[512];
  __shared__ float sxg[48];
  int t = threadIdx.x;
  int bIdx = blockIdx.x;
  int b = bIdx / HWc, hw = bIdx % HWc;
  const float* txb = tx + ((size_t)b*Cc*HWc + hw)*Ll;
  const float* tgb = tg + ((size_t)b*Cc*HWc + hw)*Ll;
  for (int q = t; q < 768; q += 256){
    int c = q / 12, v = (q % 12) << 2;
    float4 a = *(const float4*)(txb + (size_t)c*HWL + v);
    txt[v+0][c]=a.x; txt[v+1][c]=a.y; txt[v+2][c]=a.z; txt[v+3][c]=a.w;
    float4 g = *(const float4*)(tgb + (size_t)c*HWL + v);
    tgt[v+0][c]=g.x; tgt[v+1][c]=g.y; tgt[v+2][c]=g.z; tgt[v+3][c]=g.w;
  }
  __syncthreads();
  int c = t & 63, lg = t >> 6;
  float psum = 0.f, pmin = 3.4e38f;
  #pragma unroll
  for (int li = 0; li < 12; ++li){
    int l = lg*12 + li;
    float prod = txt[l][c]*tgt[l][c];
    psum += prod;
    pmin = fminf(pmin, prod);
  }
  red[t] = psum;
  if (t < 48){
    float sx = 0.f, sg = 0.f;
    #pragma unroll 8
    for (int cc = 0; cc < 64; ++cc){ sx += txt[t][cc]; sg += tgt[t][cc]; }
    sxg[t] = sx*sg;
  }
  __syncthreads();
  if (t < 64) part_row[(size_t)bIdx*64 + t] = red[t]+red[t+64]+red[t+128]+red[t+192];
  // raw theta_c_d[i,j] = sum_l txt[l][i]*tgt[l][j]; block min
  int i0 = (t & 15) << 2, j0 = (t >> 4) << 2;
  float a00=0,a01=0,a02=0,a03=0,a10=0,a11=0,a12=0,a13=0;
  float a20=0,a21=0,a22=0,a23=0,a30=0,a31=0,a32=0,a33=0;
  #pragma unroll 4
  for (int l = 0; l < 48; ++l){
    float4 av = *(const float4*)&txt[l][i0];
    float4 bv = *(const float4*)&tgt[l][j0];
    a00 += av.x*bv.x; a01 += av.x*bv.y; a02 += av.x*bv.z; a03 += av.x*bv.w;
    a10 += av.y*bv.x; a11 += av.y*bv.y; a12 += av.y*bv.z; a13 += av.y*bv.w;
    a20 += av.z*bv.x; a21 += av.z*bv.y; a22 += av.z*bv.z; a23 += av.z*bv.w;
    a30 += av.w*bv.x; a31 += av.w*bv.y; a32 += av.w*bv.z; a33 += av.w*bv.w;
  }
  float amin = fminf(fminf(fminf(a00,a01),fminf(a02,a03)),
               fminf(fminf(fminf(a10,a11),fminf(a12,a13)),
               fminf(fminf(fminf(a20,a21),fminf(a22,a23)),
                     fminf(fminf(a30,a31),fminf(a32,a33)))));
  __syncthreads();            // red reads (part_row) done
  red[t] = pmin; red[256+t] = amin;
  __syncthreads();
  if (t < 128){
    red[t] = fminf(red[t], red[t+128]);
    red[256+t] = fminf(red[256+t], red[256+t+128]);
  }
  __syncthreads();
  if (t < 64){
    float v1 = fminf(red[t], red[t+64]);
    float v2 = fminf(red[256+t], red[256+t+64]);
    #pragma unroll
    for (int off = 32; off; off >>= 1){
      v1 = fminf(v1, __shfl_down(v1, off));
      v2 = fminf(v2, __shfl_down(v2, off));
    }
    if (t == 0){
      pm1[bIdx] = v1; pm2[bIdx] = v2;
      float tot = 0.f;
      #pragma unroll
      for (int l = 0; l < 48; ++l) tot += sxg[l];
      ps2[bIdx] = tot;
    }
  }
}

// parallel second-stage reduction: 130 blocks
// blocks 0..127: rowsum for (b = blk>>6, c = blk&63)
// block 128: global mins; block 129: per-batch s2 sums
__global__ __launch_bounds__(256) void reduce2_k(const float* __restrict__ part_row,
    const float* __restrict__ pm1, const float* __restrict__ pm2,
    const float* __restrict__ ps2, float* __restrict__ rowsum,
    float* __restrict__ gmin, float* __restrict__ s2v){
  __shared__ float red[512];
  int t = threadIdx.x, blk = blockIdx.x;
  if (blk < 128){
    int b = blk >> 6, c = blk & 63;
    const float* src = part_row + (size_t)b*HWc*64 + c;
    float s = 0.f;
    #pragma unroll
    for (int k = 0; k < 9; ++k){
      int i = t + (k << 8);
      s += src[(size_t)i*64];
    }
    red[t] = s; __syncthreads();
    for (int sgap = 128; sgap >= 64; sgap >>= 1){
      if (t < sgap) red[t] += red[t+sgap];
      __syncthreads();
    }
    if (t < 64){
      float v = red[t];
      #pragma unroll
      for (int off = 32; off; off >>= 1) v += __shfl_down(v, off);
      if (t == 0) rowsum[blk] = v;
    }
  } else if (blk == 128){
    float m1 = 3.4e38f, m2 = 3.4e38f;
    for (int i = t; i < NBLK; i += 256){ m1 = fminf(m1, pm1[i]); m2 = fminf(m2, pm2[i]); }
    red[t] = m1; red[256+t] = m2; __syncthreads();
    for (int s = 128; s >= 1; s >>= 1){
      if (t < s){ red[t] = fminf(red[t], red[t+s]); red[256+t] = fminf(red[256+t], red[256+t+s]); }
      __syncthreads();
    }
    if (t == 0){ gmin[0] = red[0]; gmin[1] = red[256]; }
  } else {
    float sa = 0.f, sb = 0.f;
    for (int i = t; i < HWc; i += 256){ sa += ps2[i]; sb += ps2[HWc + i]; }
    red[t] = sa; red[256+t] = sb; __syncthreads();
    for (int s = 128; s >= 1; s >>= 1){
      if (t < s){ red[t] += red[t+s]; red[256+t] += red[256+t+s]; }
      __syncthreads();
    }
    if (t == 0){ s2v[0] = red[0]; s2v[1] = red[256]; }
  }
}

// one block per (b,h,w): compute p and d
__global__ __launch_bounds__(256) void final_k(const float* __restrict__ x,
    const float* __restrict__ tx, const float* __restrict__ tg,
    const float* __restrict__ gmin, const float* __restrict__ rowsum,
    const float* __restrict__ s2v, float* __restrict__ outp, float* __restrict__ outd){
  __shared__ __align__(16) float sh[6528 + 3328 + 48 + 64];
  float* txt = sh;           // [48][68]  l*68+c
  float* tgt = sh + 3264;    // [48][68]
  float* At  = sh;           // [64][68] aliased over txt/tgt after they die
  float* xs  = sh + 6528;    // [64][52]  c*52+l
  float* Xs  = sh + 6528 + 3328;   // [48]
  float* iv1 = Xs + 48;            // [64]
  int t = threadIdx.x;
  int bIdx = blockIdx.x;
  int b = bIdx / HWc, hw = bIdx % HWc;
  size_t sbase = ((size_t)b*Cc*HWc + hw)*Ll;
  const float* txb = tx + sbase;
  const float* tgb = tg + sbase;
  const float* xb  = x  + sbase;
  for (int q = t; q < 768; q += 256){
    int c = q / 12, v = (q % 12) << 2;
    float4 a = *(const float4*)(txb + (size_t)c*HWL + v);
    txt[(v+0)*68+c]=a.x; txt[(v+1)*68+c]=a.y; txt[(v+2)*68+c]=a.z; txt[(v+3)*68+c]=a.w;
    float4 g = *(const float4*)(tgb + (size_t)c*HWL + v);
    tgt[(v+0)*68+c]=g.x; tgt[(v+1)*68+c]=g.y; tgt[(v+2)*68+c]=g.z; tgt[(v+3)*68+c]=g.w;
    float4 xv = *(const float4*)(xb + (size_t)c*HWL + v);
    *(float4*)&xs[c*52 + v] = xv;
  }
  __syncthreads();
  if (t < 48){
    float s = 0.f;
    #pragma unroll 8
    for (int cc = 0; cc < 64; ++cc) s += xs[cc*52 + t];
    Xs[t] = s;
  }
  float m1 = gmin[0], m2 = gmin[1];
  if (t < 64) iv1[t] = 1.f/(rowsum[b*64 + t] - m1*CNT1f);
  float invd2 = 1.f/(s2v[b] - m2*CNT2f);
  // At accumulation in registers (reads txt/tgt)
  int i0 = (t & 15) << 2, j0 = (t >> 4) << 2;
  float a00=0,a01=0,a02=0,a03=0,a10=0,a11=0,a12=0,a13=0;
  float a20=0,a21=0,a22=0,a23=0,a30=0,a31=0,a32=0,a33=0;
  #pragma unroll 4
  for (int l = 0; l < 48; ++l){
    float4 av = *(const float4*)&txt[l*68 + i0];
    float4 bv = *(const float4*)&tgt[l*68 + j0];
    a00 += av.x*bv.x; a01 += av.x*bv.y; a02 += av.x*bv.z; a03 += av.x*bv.w;
    a10 += av.y*bv.x; a11 += av.y*bv.y; a12 += av.y*bv.z; a13 += av.y*bv.w;
    a20 += av.z*bv.x; a21 += av.z*bv.y; a22 += av.z*bv.z; a23 += av.z*bv.w;
    a30 += av.w*bv.x; a31 += av.w*bv.y; a32 += av.w*bv.z; a33 += av.w*bv.w;
  }
  __syncthreads();   // Xs/iv1 visible; all still need txt/tgt for p
  // p = (tx*tg - m1)*invd1[c]*x
  #pragma unroll
  for (int k = 0; k < 12; ++k){
    int e = t + (k << 8);
    int cc = e / 48, l = e % 48;
    float pv = (txt[l*68+cc]*tgt[l*68+cc] - m1)*iv1[cc]*xs[cc*52+l];
    outp[sbase + (size_t)cc*HWL + l] = pv;
  }
  __syncthreads();   // p reads of txt/tgt done; safe to overwrite with At
  { float4 r = make_float4(a00,a01,a02,a03); *(float4*)&At[(i0+0)*68 + j0] = r; }
  { float4 r = make_float4(a10,a11,a12,a13); *(float4*)&At[(i0+1)*68 + j0] = r; }
  { float4 r = make_float4(a20,a21,a22,a23); *(float4*)&At[(i0+2)*68 + j0] = r; }
  { float4 r = make_float4(a30,a31,a32,a33); *(float4*)&At[(i0+3)*68 + j0] = r; }
  __syncthreads();
  // d[j,l] = (sum_c xs[c][l]*At[c][j] - m2*Xs[l]) * invd2
  if (t < 192){
    int jj = (t & 15) << 2, l0 = (t >> 4) << 2;
    float d00=0,d01=0,d02=0,d03=0,d10=0,d11=0,d12=0,d13=0;
    float d20=0,d21=0,d22=0,d23=0,d30=0,d31=0,d32=0,d33=0;
    #pragma unroll 4
    for (int cc = 0; cc < 64; ++cc){
      float4 av = *(const float4*)&At[cc*68 + jj];
      float4 xv = *(const float4*)&xs[cc*52 + l0];
      d00 += av.x*xv.x; d01 += av.x*xv.y; d02 += av.x*xv.z; d03 += av.x*xv.w;
      d10 += av.y*xv.x; d11 += av.y*xv.y; d12 += av.y*xv.z; d13 += av.y*xv.w;
      d20 += av.z*xv.x; d21 += av.z*xv.y; d22 += av.z*xv.z; d23 += av.z*xv.w;
      d30 += av.w*xv.x; d31 += av.w*xv.y; d32 += av.w*xv.z; d33 += av.w*xv.w;
    }
    float xs0 = m2*Xs[l0+0], xs1 = m2*Xs[l0+1], xs2 = m2*Xs[l0+2], xs3 = m2*Xs[l0+3];
    { float4 r = make_float4((d00-xs0)*invd2,(d01-xs1)*invd2,(d02-xs2)*invd2,(d03-xs3)*invd2);
      *(float4*)(outd + sbase + (size_t)(jj+0)*HWL + l0) = r; }
    { float4 r = make_float4((d10-xs0)*invd2,(d11-xs1)*invd2,(d12-xs2)*invd2,(d13-xs3)*invd2);
      *(float4*)(outd + sbase + (size_t)(jj+1)*HWL + l0) = r; }
    { float4 r = make_float4((d20-xs0)*invd2,(d21-xs1)*invd2,(d22-xs2)*invd2,(d23-xs3)*invd2);
      *(float4*)(outd + sbase + (size_t)(jj+2)*HWL + l0) = r; }
    { float4 r = make_float4((d30-xs0)*invd2,(d31-xs1)*invd2,(d32-xs2)*invd2,(d33-xs3)*invd2);
      *(float4*)(outd + sbase + (size_t)(jj+3)*HWL + l0) = r; }
  }
}

extern "C" void kernel_launch(void* const* d_in, const int* in_sizes, int n_in,
                              void* d_out, int out_size, void* d_ws, size_t ws_size,
                              hipStream_t stream){
  (void)in_sizes; (void)n_in; (void)out_size; (void)ws_size;
  const float* x  = (const float*)d_in[0];
  const float* g  = (const float*)d_in[1];
  const float* W1 = (const float*)d_in[2];
  const float* b1 = (const float*)d_in[3];
  const float* W2 = (const float*)d_in[4];
  const float* b2 = (const float*)d_in[5];
  float* outp = (float*)d_out;
  float* outd = outp + (size_t)Bb*Cc*HWL;
  float* ws   = (float*)d_ws;
  float* txw  = ws;                               // 14,155,776
  float* tgw  = txw + (size_t)Bb*Cc*HWL;          // 14,155,776 (full-res theta_g)
  float* tghw = tgw + (size_t)Bb*Cc*HWL;          // 1,769,472
  float* part_row = tghw + (size_t)Bb*Cc*SG;      // NBLK*64
  float* pm1 = part_row + (size_t)NBLK*64;        // NBLK
  float* pm2 = pm1 + NBLK;                        // NBLK
  float* ps2 = pm2 + NBLK;                        // NBLK
  float* rowsum = ps2 + NBLK;                     // 128
  float* gmin = rowsum + 128;                     // 2
  float* s2v  = gmin + 2;                         // 2

  hipLaunchKernelGGL(conv_k, dim3(Bb*(SG/64)), dim3(256), 0, stream, g, W2, b2, tghw, SG);
  hipLaunchKernelGGL(conv_k, dim3(Bb*(HWL/64)), dim3(256), 0, stream, x, W1, b1, txw, HWL);
  hipLaunchKernelGGL(upsample_k, dim3(Bb*Cc*Hh), dim3(256), 0, stream, tghw, tgw);
  hipLaunchKernelGGL(reduce_k, dim3(NBLK), dim3(256), 0, stream, txw, tgw, part_row, pm1, pm2, ps2);
  hipLaunchKernelGGL(reduce2_k, dim3(130), dim3(256), 0, stream, part_row, pm1, pm2, ps2, rowsum, gmin, s2v);
  hipLaunchKernelGGL(final_k, dim3(NBLK), dim3(256), 0, stream, x, txw, tgw, gmin, rowsum, s2v, outp, outd);
}